// Round 7
// baseline (1255.547 us; speedup 1.0000x reference)
//
#include <hip/hip_runtime.h>

#define NN 20000
#define NP 20032   // padded rows (313 gemm tiles * 64)
#define EE 320000
#define TT 12
#define HH 128
#define FF 16
#define CC 16
#define HOR 6

// binning-sort parameters (CSR build)
#define NB 313      // buckets of 64 dst nodes
#define WPT 42      // binning workgroups per timestep
#define CAP 64      // per-(wg,bucket) capacity

#define NBLK 79     // ceil(NN/256) for aggX
#define NTILE 313   // 64-row gemm tiles
#define CBLK 256    // persistent-chain blocks (== CU count, all co-resident)

typedef __attribute__((ext_vector_type(8))) short short8;
typedef __attribute__((ext_vector_type(4))) float f32x4;

__device__ __forceinline__ float blo(unsigned int u) {
    union { float f; unsigned int i; } v; v.i = u << 16; return v.f;
}
__device__ __forceinline__ float bhi(unsigned int u) {
    union { float f; unsigned int i; } v; v.i = u & 0xffff0000u; return v.f;
}
__device__ __forceinline__ unsigned short f2b(float f) {
    union { float f; unsigned int i; } v; v.f = f;
    unsigned int x = v.i;
    return (unsigned short)((x + 0x7fffu + ((x >> 16) & 1u)) >> 16);
}
__device__ __forceinline__ unsigned int pck(float lo, float hi) {
    return ((unsigned int)f2b(hi) << 16) | f2b(lo);
}
__device__ __forceinline__ void addrow(float* acc, uint4 r) {
    acc[0] += blo(r.x); acc[1] += bhi(r.x);
    acc[2] += blo(r.y); acc[3] += bhi(r.y);
    acc[4] += blo(r.z); acc[5] += bhi(r.z);
    acc[6] += blo(r.w); acc[7] += bhi(r.w);
}

// ---------------- setup kernels ----------------
__global__ void k_zero(int* p, int n) {
    int i = blockIdx.x * 256 + threadIdx.x;
    if (i < n) p[i] = 0;
}

// ---- CSR build phase A: bin edges into private per-WG buckets ----
__global__ __launch_bounds__(512) void k_binA(const int* __restrict__ ei,
                                              int* __restrict__ gData,
                                              int* __restrict__ pcnt) {
    int wg = blockIdx.x;
    int t = wg / WPT, w = wg - t * WPT;
    __shared__ int lcnt[NB];
    int tid = threadIdx.x;
    for (int i = tid; i < NB; i += 512) lcnt[i] = 0;
    __syncthreads();
    const int CH = (EE + WPT - 1) / WPT;
    int e0 = w * CH, e1 = min(EE, e0 + CH);
    const int* si = ei + (size_t)t * 2 * EE;
    const int* di = si + EE;
    for (int e = e0 + tid; e < e1; e += 512) {
        int s = si[e], d = di[e];
        int b = d >> 6;
        int pos = atomicAdd(&lcnt[b], 1);
        if (pos < CAP)
            gData[((size_t)(t * WPT + w) * NB + b) * CAP + pos] = ((d & 63) << 16) | s;
    }
    __syncthreads();
    for (int i = tid; i < NB; i += 512)
        pcnt[(size_t)(t * WPT + w) * NB + i] = min(lcnt[i], CAP);
}

__global__ void k_bsum(const int* __restrict__ pcnt, int* __restrict__ bcnt) {
    int idx = blockIdx.x * 256 + threadIdx.x;
    if (idx >= TT * NB) return;
    int t = idx / NB, b = idx - t * NB;
    int s = 0;
    for (int w = 0; w < WPT; w++) s += pcnt[(size_t)(t * WPT + w) * NB + b];
    bcnt[idx] = s;
}

__global__ void k_bscan(const int* __restrict__ bcnt, int* __restrict__ bbase,
                        int* __restrict__ rowptr) {
    int t = blockIdx.x, tid = threadIdx.x;
    __shared__ int sm[512];
    int v = (tid < NB) ? bcnt[t * NB + tid] : 0;
    sm[tid] = v;
    __syncthreads();
    for (int off = 1; off < 512; off <<= 1) {
        int u = (tid >= off) ? sm[tid - off] : 0;
        __syncthreads();
        sm[tid] += u;
        __syncthreads();
    }
    if (tid < NB) bbase[t * NB + tid] = sm[tid] - v;
    if (tid == 511) rowptr[(size_t)t * (NN + 1) + NN] = sm[511];
}

__global__ __launch_bounds__(256) void k_placeB(const int* __restrict__ gData,
                                                const int* __restrict__ pcnt,
                                                const int* __restrict__ bbase,
                                                int* __restrict__ rowptr,
                                                float* __restrict__ dinv,
                                                unsigned short* __restrict__ csr) {
    int t = blockIdx.x / NB, b = blockIdx.x - t * NB;
    int tid = threadIdx.x;
    __shared__ int scnt[WPT], cofs[WPT + 1];
    __shared__ int elist[2048];
    __shared__ int cnt64[64], lofs[64], place[64];
    if (tid < WPT) scnt[tid] = pcnt[(size_t)(t * WPT + tid) * NB + b];
    if (tid < 64) cnt64[tid] = 0;
    __syncthreads();
    if (tid == 0) {
        int s = 0;
        for (int w = 0; w < WPT; w++) { cofs[w] = s; s += scnt[w]; }
        cofs[WPT] = s;
    }
    __syncthreads();
    int total = cofs[WPT];
    int wv = tid >> 6, lane = tid & 63;
    for (int w = wv; w < WPT; w += 4) {
        int c = scnt[w], o = cofs[w];
        const int* sp = gData + ((size_t)(t * WPT + w) * NB + b) * CAP;
        for (int i = lane; i < c; i += 64) elist[o + i] = sp[i];
    }
    __syncthreads();
    for (int i = tid; i < total; i += 256) atomicAdd(&cnt64[elist[i] >> 16], 1);
    __syncthreads();
    if (tid == 0) {
        int s = 0;
        for (int j = 0; j < 64; j++) { lofs[j] = s; place[j] = s; s += cnt64[j]; }
    }
    __syncthreads();
    int base = bbase[t * NB + b];
    int n = b * 64 + tid;
    if (tid < 64 && n < NN) {
        rowptr[(size_t)t * (NN + 1) + n] = base + lofs[tid];
        dinv[(size_t)t * NN + n] = rsqrtf(1.0f + (float)cnt64[tid]);
    }
    unsigned short* cbase = csr + (size_t)t * EE + base;
    for (int i = tid; i < total; i += 256) {
        int en = elist[i];
        int r = atomicAdd(&place[en >> 16], 1);
        cbase[r] = (unsigned short)(en & 0xffff);
    }
}

// ---------------- fallback CSR build (small ws_size) ----------------
__global__ void k_count(const int* __restrict__ ei, int* __restrict__ cnt) {
    int idx = blockIdx.x * 256 + threadIdx.x;
    if (idx >= TT * EE) return;
    int t = idx / EE, e = idx - t * EE;
    int d = ei[t * 2 * EE + EE + e];
    atomicAdd(&cnt[t * NN + d], 1);
}

__global__ void k_dinvF(const int* __restrict__ cnt, float* __restrict__ dinv) {
    int idx = blockIdx.x * 256 + threadIdx.x;
    if (idx >= TT * NN) return;
    dinv[idx] = 1.0f / sqrtf(1.0f + (float)cnt[idx]);
}

__global__ void k_scan(const int* __restrict__ cnt, int* __restrict__ rowptr, int* __restrict__ wofs) {
    int t = blockIdx.x;
    const int* c = cnt + t * NN;
    int* rp = rowptr + t * (NN + 1);
    int* wo = wofs + t * NN;
    __shared__ int sums[1024];
    int tid = threadIdx.x;
    const int CH2 = 20;
    int base = tid * CH2;
    int loc[CH2];
    int s = 0;
    for (int i = 0; i < CH2; i++) { int ix = base + i; int v = (ix < NN) ? c[ix] : 0; loc[i] = s; s += v; }
    sums[tid] = s;
    __syncthreads();
    for (int off = 1; off < 1024; off <<= 1) {
        int v = (tid >= off) ? sums[tid - off] : 0;
        __syncthreads();
        sums[tid] += v;
        __syncthreads();
    }
    int excl = (tid > 0) ? sums[tid - 1] : 0;
    for (int i = 0; i < CH2; i++) {
        int ix = base + i;
        if (ix < NN) { int e = excl + loc[i]; rp[ix] = e; wo[ix] = e; }
    }
    if (tid == 1023) rp[NN] = sums[1023];
}

__global__ void k_place(const int* __restrict__ ei, int* __restrict__ wofs,
                        unsigned short* __restrict__ csr) {
    int idx = blockIdx.x * 256 + threadIdx.x;
    if (idx >= TT * EE) return;
    int t = idx / EE, e = idx - t * EE;
    int s = ei[t * 2 * EE + e];
    int d = ei[t * 2 * EE + EE + e];
    int pos = atomicAdd(&wofs[t * NN + d], 1);
    csr[t * EE + pos] = (unsigned short)s;
}

// ---------------- fused TCN+proj weight prep ----------------
__global__ void k_wprep(const float* __restrict__ cw, const float* __restrict__ pw,
                        unsigned short* __restrict__ Bpk) {
    int idx = blockIdx.x * 256 + threadIdx.x;
    if (idx >= 384 * HH) return;
    int kk = idx / HH, h = idx - kk * HH;
    float m = 0.f;
    if (kk < 128) {
        int i = kk;
        for (int o = 0; o < HH; o++)
            m += cw[((1 * HH + o) * HH + i) * 3 + 0] * pw[h * 384 + 128 + o];
    } else if (kk < 256) {
        int i = kk - 128;
        for (int o = 0; o < HH; o++)
            m += cw[((0 * HH + o) * HH + i) * 3 + 0] * pw[h * 384 + o];
    } else {
        int i = kk - 256;
        for (int d = 0; d < 3; d++)
            for (int o = 0; o < HH; o++)
                m += cw[((d * HH + o) * HH + i) * 3 + 1] * pw[h * 384 + d * HH + o];
    }
    int ki = kk >> 5, r = kk & 31, q = r >> 3, j = r & 7, nt = h >> 4, ln = q * 16 + (h & 15);
    Bpk[(size_t)((ki * 8 + nt) * 64 + ln) * 8 + j] = f2b(m);
}

__global__ void k_bias(const float* __restrict__ cb, const float* __restrict__ pw,
                       const float* __restrict__ pb, float* __restrict__ bias) {
    int h = threadIdx.x;
    float m = pb[h];
    for (int d = 0; d < 3; d++)
        for (int o = 0; o < HH; o++)
            m += cb[d * HH + o] * pw[h * 384 + d * HH + o];
    bias[h] = m;
}

// ---------------- encoder front-end ----------------
// xs[t][n][k] = bf16(x[t][n][k] * dinv[t][n])  — all 12 encoder steps at once
__global__ void k_xs(const float* __restrict__ x, const float* __restrict__ dinv,
                     unsigned short* __restrict__ xs) {
    int idx = blockIdx.x * 256 + threadIdx.x;
    if (idx >= TT * NN) return;
    float dn = dinv[idx];
    const float4* xr = (const float4*)(x + (size_t)idx * FF);
    unsigned int res[8];
#pragma unroll
    for (int k = 0; k < 4; k++) {
        float4 v = xr[k];
        res[2 * k]     = pck(v.x * dn, v.y * dn);
        res[2 * k + 1] = pck(v.z * dn, v.w * dn);
    }
    uint4* dst = (uint4*)(xs + (size_t)idx * FF);
    dst[0] = *(uint4*)(res);
    dst[1] = *(uint4*)(res + 4);
}

// z[g][n][0..15] = dinv_n * (sum_{s in N(n)} xs[s] + xs[n]),  fp32 out
__global__ __launch_bounds__(256) void k_aggX(const unsigned short* __restrict__ xsA,
                                              const unsigned short* __restrict__ csrA,
                                              const int* __restrict__ rpA,
                                              const float* __restrict__ dinvA,
                                              float* __restrict__ zA) {
    int b = blockIdx.x;
    int g = b / NBLK, nb = b - g * NBLK;
    int n = nb * 256 + threadIdx.x;
    if (n >= NN) return;
    const unsigned short* xs = xsA + (size_t)g * NN * FF;
    const unsigned short* csr = csrA + (size_t)g * EE;
    const int* rp = rpA + (size_t)g * (NN + 1);
    float acc[16];
    {
        const uint4* sp = (const uint4*)(xs + (size_t)n * FF);
        uint4 a = sp[0], b4 = sp[1];
        acc[0] = blo(a.x);  acc[1] = bhi(a.x);  acc[2] = blo(a.y);  acc[3] = bhi(a.y);
        acc[4] = blo(a.z);  acc[5] = bhi(a.z);  acc[6] = blo(a.w);  acc[7] = bhi(a.w);
        acc[8] = blo(b4.x); acc[9] = bhi(b4.x); acc[10] = blo(b4.y); acc[11] = bhi(b4.y);
        acc[12] = blo(b4.z); acc[13] = bhi(b4.z); acc[14] = blo(b4.w); acc[15] = bhi(b4.w);
    }
    int j0 = rp[n], j1 = rp[n + 1];
    int j = j0;
    for (; j + 1 < j1; j += 2) {
        int s0 = csr[j], s1 = csr[j + 1];
        const uint4* p0 = (const uint4*)(xs + (size_t)s0 * FF);
        const uint4* p1 = (const uint4*)(xs + (size_t)s1 * FF);
        uint4 a0 = p0[0], a1 = p0[1], b0 = p1[0], b1 = p1[1];
        addrow(acc, a0); addrow(acc + 8, a1);
        addrow(acc, b0); addrow(acc + 8, b1);
    }
    if (j < j1) {
        const uint4* p0 = (const uint4*)(xs + (size_t)csr[j] * FF);
        uint4 a0 = p0[0], a1 = p0[1];
        addrow(acc, a0); addrow(acc + 8, a1);
    }
    float dn = dinvA[(size_t)g * NN + n];
    float4* zo = (float4*)(zA + (size_t)g * NP * FF + (size_t)n * FF);
#pragma unroll
    for (int k = 0; k < 4; k++)
        zo[k] = make_float4(acc[4 * k] * dn, acc[4 * k + 1] * dn,
                            acc[4 * k + 2] * dn, acc[4 * k + 3] * dn);
}

// hg A-fragment prologue: lane computes its 32 hg values (row wid*16+mr, cols k2*32+q*8+0..7)
__device__ __forceinline__ void hg_frag(const float* zsh, const float* Wg, const float* gbs,
                                        int wid, int mr, int q, short8* hgf) {
    float zr[16];
    {
        const float4* zp = (const float4*)(zsh + (wid * 16 + mr) * FF);
        float4 z0 = zp[0], z1 = zp[1], z2 = zp[2], z3 = zp[3];
        zr[0] = z0.x; zr[1] = z0.y; zr[2] = z0.z; zr[3] = z0.w;
        zr[4] = z1.x; zr[5] = z1.y; zr[6] = z1.z; zr[7] = z1.w;
        zr[8] = z2.x; zr[9] = z2.y; zr[10] = z2.z; zr[11] = z2.w;
        zr[12] = z3.x; zr[13] = z3.y; zr[14] = z3.z; zr[15] = z3.w;
    }
#pragma unroll
    for (int k2 = 0; k2 < 4; k2++) {
        float s[8];
#pragma unroll
        for (int c = 0; c < 8; c++) s[c] = gbs[k2 * 32 + q * 8 + c];
#pragma unroll
        for (int f = 0; f < 16; f++) {
            const float4* wp = (const float4*)(Wg + f * HH + k2 * 32 + q * 8);
            float4 w0 = wp[0], w1 = wp[1];
            float zf = zr[f];
            s[0] += zf * w0.x; s[1] += zf * w0.y; s[2] += zf * w0.z; s[3] += zf * w0.w;
            s[4] += zf * w1.x; s[5] += zf * w1.y; s[6] += zf * w1.z; s[7] += zf * w1.w;
        }
#pragma unroll
        for (int c = 0; c < 8; c++) hgf[k2][c] = (short)f2b(fmaxf(s[c], 0.f));
    }
}

// grid barrier: all CBLK blocks co-resident (grid == CU count); monotone target
__device__ __forceinline__ void gridbar(int* bar, int step) {
    __syncthreads();
    if (threadIdx.x == 0) {
        __threadfence();                       // release
        atomicAdd(bar, 1);
        int target = CBLK * (step + 1);
        while (atomicAdd(bar, 0) < target) __builtin_amdgcn_s_sleep(2);
    }
    __syncthreads();
    __threadfence();                           // acquire (all threads)
}

// ---------------- the fused 18-step recurrence ----------------
__global__ __launch_bounds__(256) void k_chain(
    unsigned short* b0, unsigned short* b1, unsigned short* b2,
    const float* __restrict__ z12, const float* __restrict__ gw,
    const float* __restrict__ gb, const unsigned short* __restrict__ Bpk,
    const float* __restrict__ bias, const float* __restrict__ hw,
    const float* __restrict__ hbv, const float* __restrict__ dinv11,
    const int* __restrict__ rp11, const unsigned short* __restrict__ csr11,
    unsigned short* xsD0, unsigned short* xsD1,
    float* __restrict__ yout, int* bar) {
    __shared__ float Wg[FF * HH];
    __shared__ float Wh[CC * HH];
    __shared__ float gbs[HH], biasS[HH], hbS[CC];
    __shared__ float zsh[64 * FF];
    __shared__ unsigned short hsh[64 * 136];
    int tid = threadIdx.x;
    for (int i = tid; i < FF * HH; i += 256) { Wg[i] = gw[i]; Wh[i] = hw[i]; }
    if (tid < HH) { gbs[tid] = gb[tid]; biasS[tid] = bias[tid]; }
    if (tid < CC) hbS[tid] = hbv[tid];
    unsigned short* hb[3] = {b0, b1, b2};
    unsigned short* xsbuf[2] = {xsD0, xsD1};
    int wid = tid >> 6, lane = tid & 63, mr = lane & 15, q = lane >> 4;
    int ntl = ((int)blockIdx.x < (NTILE - CBLK)) ? 2 : 1;
    for (int t = 0; t < TT + HOR; t++) {
        unsigned short* out = hb[t % 3];
        const unsigned short* a0 = hb[(t + 1) % 3];
        const unsigned short* a1 = hb[(t + 2) % 3];
        const unsigned short* xsR = xsbuf[t & 1];        // decoder gather source
        unsigned short* xsW = xsbuf[(t + 1) & 1];        // decoder feedback target
        for (int ti = 0; ti < ntl; ti++) {
            int m0b = ((int)blockIdx.x + ti * CBLK) * 64;
            __syncthreads();   // protect zsh/hsh reuse across tiles/steps
            if (t <= TT) {
                const float* z = z12 + (size_t)((t < TT) ? t : (TT - 1)) * NP * FF;
                for (int i = tid; i < 64 * FF; i += 256) zsh[i] = z[(size_t)m0b * FF + i];
            } else {
                // in-kernel 16-dim aggregation from xsR (4 threads/row)
                int r = tid >> 2, p = tid & 3, half = p & 1, eo = p >> 1;
                int n = m0b + r;
                float a[8];
#pragma unroll
                for (int k = 0; k < 8; k++) a[k] = 0.f;
                if (n < NN) {
                    int j0 = rp11[n], j1 = rp11[n + 1];
                    for (int j = j0 + eo; j < j1; j += 2) {
                        int s = csr11[j];
                        uint4 v = *(const uint4*)(xsR + (size_t)s * FF + half * 8);
                        addrow(a, v);
                    }
                }
#pragma unroll
                for (int k = 0; k < 8; k++) a[k] += __shfl_xor(a[k], 2);
                if (n < NN && eo == 0) {
                    uint4 sv = *(const uint4*)(xsR + (size_t)n * FF + half * 8);
                    addrow(a, sv);
                    float dn = dinv11[n];
#pragma unroll
                    for (int k = 0; k < 8; k++) zsh[r * FF + half * 8 + k] = a[k] * dn;
                }
            }
            __syncthreads();
            short8 hgf[4];
            hg_frag(zsh, Wg, gbs, wid, mr, q, hgf);
            f32x4 acc[8];
#pragma unroll
            for (int i = 0; i < 8; i++) acc[i] = (f32x4){0.f, 0.f, 0.f, 0.f};
            int m0 = m0b + wid * 16;
#pragma unroll
            for (int ki = 0; ki < 8; ki++) {
                const unsigned short* Ab = (ki < 4) ? a0 : a1;
                int kin = (ki & 3) * 32 + q * 8;
                short8 af = *(const short8*)(Ab + (size_t)(m0 + mr) * HH + kin);
#pragma unroll
                for (int nt = 0; nt < 8; nt++) {
                    short8 bf = *(const short8*)(Bpk + (size_t)((ki * 8 + nt) * 64 + lane) * 8);
                    acc[nt] = __builtin_amdgcn_mfma_f32_16x16x32_bf16(af, bf, acc[nt], 0, 0, 0);
                }
            }
#pragma unroll
            for (int k2 = 0; k2 < 4; k2++) {
#pragma unroll
                for (int nt = 0; nt < 8; nt++) {
                    short8 bf = *(const short8*)(Bpk + (size_t)(((8 + k2) * 8 + nt) * 64 + lane) * 8);
                    acc[nt] = __builtin_amdgcn_mfma_f32_16x16x32_bf16(hgf[k2], bf, acc[nt], 0, 0, 0);
                }
            }
            if (t < TT) {
#pragma unroll
                for (int nt = 0; nt < 8; nt++) {
                    int feat = nt * 16 + mr;
                    float bv = biasS[feat];
#pragma unroll
                    for (int r = 0; r < 4; r++)
                        out[(size_t)(m0 + q * 4 + r) * HH + feat] = f2b(acc[nt][r] + bv);
                }
            } else {
#pragma unroll
                for (int nt = 0; nt < 8; nt++) {
                    int feat = nt * 16 + mr;
                    float bv = biasS[feat];
#pragma unroll
                    for (int r = 0; r < 4; r++) {
                        int lrow = wid * 16 + q * 4 + r;
                        unsigned short hv = f2b(acc[nt][r] + bv);
                        out[(size_t)(m0b + lrow) * HH + feat] = hv;
                        hsh[lrow * 136 + feat] = hv;
                    }
                }
                __syncthreads();
                // head + feedback: y = h@Wh^T + hb ; xsW = bf16(y*dinv)
                int r = tid >> 2, c0 = (tid & 3) * 4;
                float y0 = hbS[c0], y1 = hbS[c0 + 1], y2 = hbS[c0 + 2], y3 = hbS[c0 + 3];
                for (int k = 0; k < HH; k++) {
                    float hv = blo((unsigned int)hsh[r * 136 + k]);
                    y0 += hv * Wh[(c0 + 0) * HH + k];
                    y1 += hv * Wh[(c0 + 1) * HH + k];
                    y2 += hv * Wh[(c0 + 2) * HH + k];
                    y3 += hv * Wh[(c0 + 3) * HH + k];
                }
                int gn = m0b + r;
                if (gn < NN) {
                    *(float4*)(yout + (size_t)(t - TT) * NN * CC + (size_t)gn * CC + c0) =
                        make_float4(y0, y1, y2, y3);
                    float dn = dinv11[gn];
                    uint2 xo;
                    xo.x = pck(y0 * dn, y1 * dn);
                    xo.y = pck(y2 * dn, y3 * dn);
                    *(uint2*)(xsW + (size_t)gn * FF + c0) = xo;
                }
            }
        }
        if (t < TT + HOR - 1) gridbar(bar, t);
    }
}

extern "C" void kernel_launch(void* const* d_in, const int* in_sizes, int n_in,
                              void* d_out, int out_size, void* d_ws, size_t ws_size,
                              hipStream_t stream) {
    const float* x_seq  = (const float*)d_in[0];
    const int*   ei     = (const int*)d_in[1];
    const float* gcn_w  = (const float*)d_in[5];
    const float* gcn_b  = (const float*)d_in[6];
    const float* conv_w = (const float*)d_in[7];
    const float* conv_b = (const float*)d_in[8];
    const float* proj_w = (const float*)d_in[9];
    const float* proj_b = (const float*)d_in[10];
    const float* head_w = (const float*)d_in[11];
    const float* head_b = (const float*)d_in[12];
    float* outp = (float*)d_out;

    char* ws = (char*)d_ws;
    size_t off = 0;
    auto alloc = [&](size_t bytes) { void* p = ws + off; off += (bytes + 255) & ~(size_t)255; return p; };
    // persistent
    float*          dinv   = (float*)alloc((size_t)TT * NN * 4);
    int*            rowptr = (int*)alloc((size_t)TT * (NN + 1) * 4);
    unsigned short* csr    = (unsigned short*)alloc((size_t)TT * EE * 2);
    unsigned short* hb0    = (unsigned short*)alloc((size_t)NP * HH * 2);
    unsigned short* hb1    = (unsigned short*)alloc((size_t)NP * HH * 2);
    unsigned short* hb2    = (unsigned short*)alloc((size_t)NP * HH * 2);
    int*            bar    = (int*)alloc(256);          // right after hb2 (zeroed together)
    unsigned short* xsD0   = (unsigned short*)alloc((size_t)NP * FF * 2);
    unsigned short* xsD1   = (unsigned short*)alloc((size_t)NP * FF * 2);
    unsigned short* Bpk    = (unsigned short*)alloc((size_t)384 * HH * 2);
    float*          biasT  = (float*)alloc(HH * 4);
    // transient B: encoder xs + z (all 12 steps)
    size_t tb = off;
    unsigned short* xs12 = (unsigned short*)alloc((size_t)TT * NN * FF * 2);
    float*          z12  = (float*)alloc((size_t)TT * NP * FF * 4);
    size_t compute_end = off;
    // transient A: CSR-build scratch, aliased over transient B
    off = tb;
    int* gData = (int*)alloc((size_t)TT * WPT * NB * CAP * 4);
    int* pcnt  = (int*)alloc((size_t)TT * WPT * NB * 4);
    int* bcnt  = (int*)alloc((size_t)TT * NB * 4);
    int* bbase = (int*)alloc((size_t)TT * NB * 4);
    size_t csr_end = off;
    bool fastcsr = (csr_end <= ws_size && compute_end <= ws_size);

    // zero h-history window + barrier counter (contiguous: hb0..hb2, bar)
    k_zero<<<(3 * NP * HH / 2 + 64 + 255) / 256, 256, 0, stream>>>((int*)hb0,
                                                                   3 * NP * HH / 2 + 64);

    if (fastcsr) {
        k_binA<<<TT * WPT, 512, 0, stream>>>(ei, gData, pcnt);
        k_bsum<<<(TT * NB + 255) / 256, 256, 0, stream>>>(pcnt, bcnt);
        k_bscan<<<TT, 512, 0, stream>>>(bcnt, bbase, rowptr);
        k_placeB<<<TT * NB, 256, 0, stream>>>(gData, pcnt, bbase, rowptr, dinv, csr);
    } else {
        off = tb;
        int* cnt  = (int*)alloc((size_t)TT * NN * 4);
        int* wofs = (int*)alloc((size_t)TT * NN * 4);
        k_zero<<<(TT * NN + 255) / 256, 256, 0, stream>>>(cnt, TT * NN);
        k_count<<<(TT * EE + 255) / 256, 256, 0, stream>>>(ei, cnt);
        k_dinvF<<<(TT * NN + 255) / 256, 256, 0, stream>>>(cnt, dinv);
        k_scan<<<TT, 1024, 0, stream>>>(cnt, rowptr, wofs);
        k_place<<<(TT * EE + 255) / 256, 256, 0, stream>>>(ei, wofs, csr);
    }

    k_wprep<<<(384 * HH + 255) / 256, 256, 0, stream>>>(conv_w, proj_w, Bpk);
    k_bias<<<1, HH, 0, stream>>>(conv_b, proj_w, proj_b, biasT);

    // encoder front-end: xs for all 12 steps, then all 12 aggregations in one launch
    k_xs<<<(TT * NN + 255) / 256, 256, 0, stream>>>(x_seq, dinv, xs12);
    k_aggX<<<TT * NBLK, 256, 0, stream>>>(xs12, csr, rowptr, dinv, z12);

    // the whole 18-step recurrence in one persistent kernel
    k_chain<<<CBLK, 256, 0, stream>>>(hb0, hb1, hb2, z12, gcn_w, gcn_b, Bpk, biasT,
                                      head_w, head_b, dinv + (size_t)(TT - 1) * NN,
                                      rowptr + (size_t)(TT - 1) * (NN + 1),
                                      csr + (size_t)(TT - 1) * EE,
                                      xsD0, xsD1, outp, bar);
}

// Round 8
// 665.066 us; speedup vs baseline: 1.8879x; 1.8879x over previous
//
#include <hip/hip_runtime.h>

#define NN 20000
#define NP 20032   // padded rows (313 gemm tiles * 64)
#define EE 320000
#define TT 12
#define HH 128
#define FF 16
#define CC 16
#define HOR 6

// binning-sort parameters (CSR build)
#define NB 313      // buckets of 64 dst nodes
#define WPT 42      // binning workgroups per timestep
#define CAP 64      // per-(wg,bucket) capacity

#define NBLK 79     // ceil(NN/256) for aggX

typedef __attribute__((ext_vector_type(8))) short short8;
typedef __attribute__((ext_vector_type(4))) float f32x4;

__device__ __forceinline__ float blo(unsigned int u) {
    union { float f; unsigned int i; } v; v.i = u << 16; return v.f;
}
__device__ __forceinline__ float bhi(unsigned int u) {
    union { float f; unsigned int i; } v; v.i = u & 0xffff0000u; return v.f;
}
__device__ __forceinline__ unsigned short f2b(float f) {
    union { float f; unsigned int i; } v; v.f = f;
    unsigned int x = v.i;
    return (unsigned short)((x + 0x7fffu + ((x >> 16) & 1u)) >> 16);
}
__device__ __forceinline__ unsigned int pck(float lo, float hi) {
    return ((unsigned int)f2b(hi) << 16) | f2b(lo);
}
__device__ __forceinline__ void addrow(float* acc, uint4 r) {
    acc[0] += blo(r.x); acc[1] += bhi(r.x);
    acc[2] += blo(r.y); acc[3] += bhi(r.y);
    acc[4] += blo(r.z); acc[5] += bhi(r.z);
    acc[6] += blo(r.w); acc[7] += bhi(r.w);
}

// ---------------- setup kernels ----------------
__global__ void k_zero(int* p, int n) {
    int i = blockIdx.x * 256 + threadIdx.x;
    if (i < n) p[i] = 0;
}

// ---- CSR build phase A: bin edges into private per-WG buckets ----
__global__ __launch_bounds__(512) void k_binA(const int* __restrict__ ei,
                                              int* __restrict__ gData,
                                              int* __restrict__ pcnt) {
    int wg = blockIdx.x;
    int t = wg / WPT, w = wg - t * WPT;
    __shared__ int lcnt[NB];
    int tid = threadIdx.x;
    for (int i = tid; i < NB; i += 512) lcnt[i] = 0;
    __syncthreads();
    const int CH = (EE + WPT - 1) / WPT;
    int e0 = w * CH, e1 = min(EE, e0 + CH);
    const int* si = ei + (size_t)t * 2 * EE;
    const int* di = si + EE;
    for (int e = e0 + tid; e < e1; e += 512) {
        int s = si[e], d = di[e];
        int b = d >> 6;
        int pos = atomicAdd(&lcnt[b], 1);
        if (pos < CAP)
            gData[((size_t)(t * WPT + w) * NB + b) * CAP + pos] = ((d & 63) << 16) | s;
    }
    __syncthreads();
    for (int i = tid; i < NB; i += 512)
        pcnt[(size_t)(t * WPT + w) * NB + i] = min(lcnt[i], CAP);
}

// ---- fused bucket-sum + exclusive scan per timestep ----
__global__ __launch_bounds__(512) void k_bscan2(const int* __restrict__ pcnt,
                                                int* __restrict__ bbase,
                                                int* __restrict__ rowptr) {
    int t = blockIdx.x, tid = threadIdx.x;
    __shared__ int sm[512];
    int v = 0;
    if (tid < NB)
        for (int w = 0; w < WPT; w++) v += pcnt[(size_t)(t * WPT + w) * NB + tid];
    sm[tid] = v;
    __syncthreads();
    for (int off = 1; off < 512; off <<= 1) {
        int u = (tid >= off) ? sm[tid - off] : 0;
        __syncthreads();
        sm[tid] += u;
        __syncthreads();
    }
    if (tid < NB) bbase[t * NB + tid] = sm[tid] - v;
    if (tid == 511) rowptr[(size_t)t * (NN + 1) + NN] = sm[511];
}

__global__ __launch_bounds__(256) void k_placeB(const int* __restrict__ gData,
                                                const int* __restrict__ pcnt,
                                                const int* __restrict__ bbase,
                                                int* __restrict__ rowptr,
                                                float* __restrict__ dinv,
                                                unsigned short* __restrict__ csr) {
    int t = blockIdx.x / NB, b = blockIdx.x - t * NB;
    int tid = threadIdx.x;
    __shared__ int scnt[WPT], cofs[WPT + 1];
    __shared__ int elist[2048];
    __shared__ int cnt64[64], lofs[64], place[64];
    if (tid < WPT) scnt[tid] = pcnt[(size_t)(t * WPT + tid) * NB + b];
    if (tid < 64) cnt64[tid] = 0;
    __syncthreads();
    if (tid == 0) {
        int s = 0;
        for (int w = 0; w < WPT; w++) { cofs[w] = s; s += scnt[w]; }
        cofs[WPT] = s;
    }
    __syncthreads();
    int total = cofs[WPT];
    int wv = tid >> 6, lane = tid & 63;
    for (int w = wv; w < WPT; w += 4) {
        int c = scnt[w], o = cofs[w];
        const int* sp = gData + ((size_t)(t * WPT + w) * NB + b) * CAP;
        for (int i = lane; i < c; i += 64) elist[o + i] = sp[i];
    }
    __syncthreads();
    for (int i = tid; i < total; i += 256) atomicAdd(&cnt64[elist[i] >> 16], 1);
    __syncthreads();
    if (tid == 0) {
        int s = 0;
        for (int j = 0; j < 64; j++) { lofs[j] = s; place[j] = s; s += cnt64[j]; }
    }
    __syncthreads();
    int base = bbase[t * NB + b];
    int n = b * 64 + tid;
    if (tid < 64 && n < NN) {
        rowptr[(size_t)t * (NN + 1) + n] = base + lofs[tid];
        dinv[(size_t)t * NN + n] = rsqrtf(1.0f + (float)cnt64[tid]);
    }
    unsigned short* cbase = csr + (size_t)t * EE + base;
    for (int i = tid; i < total; i += 256) {
        int en = elist[i];
        int r = atomicAdd(&place[en >> 16], 1);
        cbase[r] = (unsigned short)(en & 0xffff);
    }
}

// ---------------- fallback CSR build (small ws_size) ----------------
__global__ void k_count(const int* __restrict__ ei, int* __restrict__ cnt) {
    int idx = blockIdx.x * 256 + threadIdx.x;
    if (idx >= TT * EE) return;
    int t = idx / EE, e = idx - t * EE;
    int d = ei[t * 2 * EE + EE + e];
    atomicAdd(&cnt[t * NN + d], 1);
}

__global__ void k_dinvF(const int* __restrict__ cnt, float* __restrict__ dinv) {
    int idx = blockIdx.x * 256 + threadIdx.x;
    if (idx >= TT * NN) return;
    dinv[idx] = 1.0f / sqrtf(1.0f + (float)cnt[idx]);
}

__global__ void k_scan(const int* __restrict__ cnt, int* __restrict__ rowptr, int* __restrict__ wofs) {
    int t = blockIdx.x;
    const int* c = cnt + t * NN;
    int* rp = rowptr + t * (NN + 1);
    int* wo = wofs + t * NN;
    __shared__ int sums[1024];
    int tid = threadIdx.x;
    const int CH2 = 20;
    int base = tid * CH2;
    int loc[CH2];
    int s = 0;
    for (int i = 0; i < CH2; i++) { int ix = base + i; int v = (ix < NN) ? c[ix] : 0; loc[i] = s; s += v; }
    sums[tid] = s;
    __syncthreads();
    for (int off = 1; off < 1024; off <<= 1) {
        int v = (tid >= off) ? sums[tid - off] : 0;
        __syncthreads();
        sums[tid] += v;
        __syncthreads();
    }
    int excl = (tid > 0) ? sums[tid - 1] : 0;
    for (int i = 0; i < CH2; i++) {
        int ix = base + i;
        if (ix < NN) { int e = excl + loc[i]; rp[ix] = e; wo[ix] = e; }
    }
    if (tid == 1023) rp[NN] = sums[1023];
}

__global__ void k_place(const int* __restrict__ ei, int* __restrict__ wofs,
                        unsigned short* __restrict__ csr) {
    int idx = blockIdx.x * 256 + threadIdx.x;
    if (idx >= TT * EE) return;
    int t = idx / EE, e = idx - t * EE;
    int s = ei[t * 2 * EE + e];
    int d = ei[t * 2 * EE + EE + e];
    int pos = atomicAdd(&wofs[t * NN + d], 1);
    csr[t * EE + pos] = (unsigned short)s;
}

// ---------------- fused TCN+proj weight prep (+ bias block) ----------------
// Writes fp32 Bcat (Bf32[384][128]) and bf16 MFMA-packed Bpk.
__global__ void k_wprepB(const float* __restrict__ cw, const float* __restrict__ pw,
                         const float* __restrict__ cb, const float* __restrict__ pb,
                         unsigned short* __restrict__ Bpk, float* __restrict__ Bf32,
                         float* __restrict__ bias) {
    int idx = blockIdx.x * 256 + threadIdx.x;
    if (blockIdx.x == 192) {
        int h = threadIdx.x;
        if (h < HH) {
            float m = pb[h];
            for (int d = 0; d < 3; d++)
                for (int o = 0; o < HH; o++)
                    m += cb[d * HH + o] * pw[h * 384 + d * HH + o];
            bias[h] = m;
        }
        return;
    }
    if (idx >= 384 * HH) return;
    int kk = idx / HH, h = idx - kk * HH;
    float m = 0.f;
    if (kk < 128) {
        int i = kk;
        for (int o = 0; o < HH; o++)
            m += cw[((1 * HH + o) * HH + i) * 3 + 0] * pw[h * 384 + 128 + o];
    } else if (kk < 256) {
        int i = kk - 128;
        for (int o = 0; o < HH; o++)
            m += cw[((0 * HH + o) * HH + i) * 3 + 0] * pw[h * 384 + o];
    } else {
        int i = kk - 256;
        for (int d = 0; d < 3; d++)
            for (int o = 0; o < HH; o++)
                m += cw[((d * HH + o) * HH + i) * 3 + 1] * pw[h * 384 + d * HH + o];
    }
    Bf32[kk * HH + h] = m;
    int ki = kk >> 5, r = kk & 31, q = r >> 3, j = r & 7, nt = h >> 4, ln = q * 16 + (h & 15);
    Bpk[(size_t)((ki * 8 + nt) * 64 + ln) * 8 + j] = f2b(m);
}

// ---------------- pairwise-step weight build ----------------
// Bpair (K=512, N=256) packed [(kb*16+nt)*64+ln]*8+j :
//   kb group g=kb>>2: 0:h_{t-2} 1:h_{t-1} 2:hg_t 3:hg_{t+1}; side s=nt>>3 (0:h_t 1:h_{t+1})
//   g0: s0=M2,        s1=M2*M1
//   g1: s0=M1,        s1=M2 + M1*M1
//   g2: s0=Mh,        s1=Mh*M1
//   g3: s0=0,         s1=Mh
// biasP[256]: [0:128)=biasT ; [128:256)=biasT + biasT*M1
__global__ __launch_bounds__(256) void k_packP(const float* __restrict__ Bf32,
                                               const float* __restrict__ biasT,
                                               unsigned short* __restrict__ Bpk2,
                                               float* __restrict__ biasP) {
    int gidx = blockIdx.x * 256 + threadIdx.x;
    if (gidx < 16 * 16 * 64 * 8) {
        int j = gidx & 7, ln = (gidx >> 3) & 63, nt = (gidx >> 9) & 15, kb = gidx >> 13;
        int q = ln >> 4;
        int kk = (kb & 3) * 32 + q * 8 + j;      // row within the 128-slice
        int c = nt * 16 + (ln & 15);             // global output col 0..255
        int s = c >> 7, h = c & 127;
        int g = kb >> 2;
        const float* M2 = Bf32;
        const float* M1 = Bf32 + 128 * HH;
        const float* Mh = Bf32 + 256 * HH;
        float v = 0.f;
        if (g == 0) {
            if (s == 0) v = M2[kk * HH + h];
            else { for (int o = 0; o < HH; o++) v += M2[kk * HH + o] * M1[o * HH + h]; }
        } else if (g == 1) {
            if (s == 0) v = M1[kk * HH + h];
            else {
                v = M2[kk * HH + h];
                for (int o = 0; o < HH; o++) v += M1[kk * HH + o] * M1[o * HH + h];
            }
        } else if (g == 2) {
            if (s == 0) v = Mh[kk * HH + h];
            else { for (int o = 0; o < HH; o++) v += Mh[kk * HH + o] * M1[o * HH + h]; }
        } else {
            v = (s == 0) ? 0.f : Mh[kk * HH + h];
        }
        Bpk2[gidx] = f2b(v);
    } else if (gidx < 16 * 16 * 64 * 8 + 256) {
        int c = gidx - 16 * 16 * 64 * 8;
        if (c < 128) biasP[c] = biasT[c];
        else {
            int h = c & 127;
            float v = biasT[h];
            const float* M1 = Bf32 + 128 * HH;
            for (int o = 0; o < HH; o++) v += biasT[o] * M1[o * HH + h];
            biasP[c] = v;
        }
    }
}

// ---------------- encoder front-end ----------------
__global__ void k_xs(const float* __restrict__ x, const float* __restrict__ dinv,
                     unsigned short* __restrict__ xs) {
    int idx = blockIdx.x * 256 + threadIdx.x;
    if (idx >= TT * NN) return;
    float dn = dinv[idx];
    const float4* xr = (const float4*)(x + (size_t)idx * FF);
    unsigned int res[8];
#pragma unroll
    for (int k = 0; k < 4; k++) {
        float4 v = xr[k];
        res[2 * k]     = pck(v.x * dn, v.y * dn);
        res[2 * k + 1] = pck(v.z * dn, v.w * dn);
    }
    uint4* dst = (uint4*)(xs + (size_t)idx * FF);
    dst[0] = *(uint4*)(res);
    dst[1] = *(uint4*)(res + 4);
}

__global__ __launch_bounds__(256) void k_aggX(const unsigned short* __restrict__ xsA,
                                              const unsigned short* __restrict__ csrA,
                                              const int* __restrict__ rpA,
                                              const float* __restrict__ dinvA,
                                              float* __restrict__ zA) {
    int b = blockIdx.x;
    int g = b / NBLK, nb = b - g * NBLK;
    int n = nb * 256 + threadIdx.x;
    if (n >= NN) return;
    const unsigned short* xs = xsA + (size_t)g * NN * FF;
    const unsigned short* csr = csrA + (size_t)g * EE;
    const int* rp = rpA + (size_t)g * (NN + 1);
    float acc[16];
    {
        const uint4* sp = (const uint4*)(xs + (size_t)n * FF);
        uint4 a = sp[0], b4 = sp[1];
        acc[0] = blo(a.x);  acc[1] = bhi(a.x);  acc[2] = blo(a.y);  acc[3] = bhi(a.y);
        acc[4] = blo(a.z);  acc[5] = bhi(a.z);  acc[6] = blo(a.w);  acc[7] = bhi(a.w);
        acc[8] = blo(b4.x); acc[9] = bhi(b4.x); acc[10] = blo(b4.y); acc[11] = bhi(b4.y);
        acc[12] = blo(b4.z); acc[13] = bhi(b4.z); acc[14] = blo(b4.w); acc[15] = bhi(b4.w);
    }
    int j0 = rp[n], j1 = rp[n + 1];
    int j = j0;
    for (; j + 1 < j1; j += 2) {
        int s0 = csr[j], s1 = csr[j + 1];
        const uint4* p0 = (const uint4*)(xs + (size_t)s0 * FF);
        const uint4* p1 = (const uint4*)(xs + (size_t)s1 * FF);
        uint4 a0 = p0[0], a1 = p0[1], b0 = p1[0], b1 = p1[1];
        addrow(acc, a0); addrow(acc + 8, a1);
        addrow(acc, b0); addrow(acc + 8, b1);
    }
    if (j < j1) {
        const uint4* p0 = (const uint4*)(xs + (size_t)csr[j] * FF);
        uint4 a0 = p0[0], a1 = p0[1];
        addrow(acc, a0); addrow(acc + 8, a1);
    }
    float dn = dinvA[(size_t)g * NN + n];
    float4* zo = (float4*)(zA + (size_t)g * NP * FF + (size_t)n * FF);
#pragma unroll
    for (int k = 0; k < 4; k++)
        zo[k] = make_float4(acc[4 * k] * dn, acc[4 * k + 1] * dn,
                            acc[4 * k + 2] * dn, acc[4 * k + 3] * dn);
}

// hg A-fragment prologue: lane computes its 32 hg values (row wid*16+mr, cols k2*32+q*8+0..7)
__device__ __forceinline__ void hg_frag(const float* zsh, const float* Wg, const float* gbs,
                                        int wid, int mr, int q, short8* hgf) {
    float zr[16];
    {
        const float4* zp = (const float4*)(zsh + (wid * 16 + mr) * FF);
        float4 z0 = zp[0], z1 = zp[1], z2 = zp[2], z3 = zp[3];
        zr[0] = z0.x; zr[1] = z0.y; zr[2] = z0.z; zr[3] = z0.w;
        zr[4] = z1.x; zr[5] = z1.y; zr[6] = z1.z; zr[7] = z1.w;
        zr[8] = z2.x; zr[9] = z2.y; zr[10] = z2.z; zr[11] = z2.w;
        zr[12] = z3.x; zr[13] = z3.y; zr[14] = z3.z; zr[15] = z3.w;
    }
#pragma unroll
    for (int k2 = 0; k2 < 4; k2++) {
        float s[8];
#pragma unroll
        for (int c = 0; c < 8; c++) s[c] = gbs[k2 * 32 + q * 8 + c];
#pragma unroll
        for (int f = 0; f < 16; f++) {
            const float4* wp = (const float4*)(Wg + f * HH + k2 * 32 + q * 8);
            float4 w0 = wp[0], w1 = wp[1];
            float zf = zr[f];
            s[0] += zf * w0.x; s[1] += zf * w0.y; s[2] += zf * w0.z; s[3] += zf * w0.w;
            s[4] += zf * w1.x; s[5] += zf * w1.y; s[6] += zf * w1.z; s[7] += zf * w1.w;
        }
#pragma unroll
        for (int c = 0; c < 8; c++) hgf[k2][c] = (short)f2b(fmaxf(s[c], 0.f));
    }
}

// ---------------- pairwise encoder gemm: (h_t, h_{t+1}) in one pass ----------------
__global__ __launch_bounds__(256) void k_gemm2(const unsigned short* __restrict__ a0,
                                               const unsigned short* __restrict__ a1,
                                               const float* __restrict__ zA,
                                               const float* __restrict__ zB,
                                               const float* __restrict__ gw,
                                               const float* __restrict__ gb,
                                               const unsigned short* __restrict__ Bpk2,
                                               const float* __restrict__ biasP,
                                               unsigned short* __restrict__ out0,
                                               unsigned short* __restrict__ out1) {
    __shared__ float Wg[FF * HH];
    __shared__ float zshA[64 * FF], zshB[64 * FF];
    __shared__ float gbs[HH];
    __shared__ float bps[256];
    int tid = threadIdx.x;
    int wid = tid >> 6, lane = tid & 63;
    int m0b = blockIdx.x * 64, m0 = m0b + wid * 16;
    int mr = lane & 15, q = lane >> 4;
    for (int i = tid; i < FF * HH; i += 256) Wg[i] = gw[i];
    for (int i = tid; i < 64 * FF; i += 256) {
        zshA[i] = zA[(size_t)m0b * FF + i];
        zshB[i] = zB[(size_t)m0b * FF + i];
    }
    if (tid < HH) gbs[tid] = gb[tid];
    bps[tid] = biasP[tid];
    __syncthreads();
    short8 hgfA[4], hgfB[4];
    hg_frag(zshA, Wg, gbs, wid, mr, q, hgfA);
    hg_frag(zshB, Wg, gbs, wid, mr, q, hgfB);
    short8 af0[4], af1[4];
#pragma unroll
    for (int k = 0; k < 4; k++) {
        af0[k] = *(const short8*)(a0 + (size_t)(m0 + mr) * HH + k * 32 + q * 8);
        af1[k] = *(const short8*)(a1 + (size_t)(m0 + mr) * HH + k * 32 + q * 8);
    }
    f32x4 acc[16];
#pragma unroll
    for (int i = 0; i < 16; i++) acc[i] = (f32x4){0.f, 0.f, 0.f, 0.f};
#pragma unroll
    for (int kb = 0; kb < 12; kb++) {
        short8 src = (kb < 4) ? af0[kb] : (kb < 8) ? af1[kb - 4] : hgfA[kb - 8];
#pragma unroll
        for (int nt = 0; nt < 16; nt++) {
            short8 bf = *(const short8*)(Bpk2 + (size_t)((kb * 16 + nt) * 64 + lane) * 8);
            acc[nt] = __builtin_amdgcn_mfma_f32_16x16x32_bf16(src, bf, acc[nt], 0, 0, 0);
        }
    }
#pragma unroll
    for (int kb = 12; kb < 16; kb++) {
        short8 src = hgfB[kb - 12];
#pragma unroll
        for (int nt = 8; nt < 16; nt++) {
            short8 bf = *(const short8*)(Bpk2 + (size_t)((kb * 16 + nt) * 64 + lane) * 8);
            acc[nt] = __builtin_amdgcn_mfma_f32_16x16x32_bf16(src, bf, acc[nt], 0, 0, 0);
        }
    }
#pragma unroll
    for (int nt = 0; nt < 16; nt++) {
        int c = nt * 16 + mr;
        float bv = bps[c];
#pragma unroll
        for (int r = 0; r < 4; r++) {
            int node = m0 + q * 4 + r;
            unsigned short v = f2b(acc[nt][r] + bv);
            if (c < 128) out0[(size_t)node * HH + c] = v;
            else         out1[(size_t)node * HH + (c - 128)] = v;
        }
    }
}

// ---------------- decoder fused step: [gather] + gemm + head + feedback ----------------
__global__ __launch_bounds__(256) void k_gemmF2(const unsigned short* __restrict__ a0,
                                                const unsigned short* __restrict__ a1,
                                                const float* __restrict__ zt, int gather,
                                                const float* __restrict__ gw,
                                                const float* __restrict__ gb,
                                                const unsigned short* __restrict__ Bpk,
                                                const float* __restrict__ bias,
                                                unsigned short* __restrict__ out,
                                                const float* __restrict__ hw,
                                                const float* __restrict__ hbv,
                                                const float* __restrict__ dinvN,
                                                const int* __restrict__ rp,
                                                const unsigned short* __restrict__ csr,
                                                unsigned short* __restrict__ xsD,
                                                float* __restrict__ yout) {
    __shared__ float Wg[FF * HH];
    __shared__ float Wh[CC * HH];
    __shared__ float gbs[HH], biasS[HH], hbS[CC];
    __shared__ float zsh[64 * FF];
    __shared__ unsigned short hsh[64 * 136];
    __shared__ float ysh[64 * 17];
    int tid = threadIdx.x;
    int wid = tid >> 6, lane = tid & 63;
    int m0b = blockIdx.x * 64, m0 = m0b + wid * 16;
    int mr = lane & 15, q = lane >> 4;
    for (int i = tid; i < FF * HH; i += 256) { Wg[i] = gw[i]; Wh[i] = hw[i]; }
    if (tid < HH) { gbs[tid] = gb[tid]; biasS[tid] = bias[tid]; }
    if (tid < CC) hbS[tid] = hbv[tid];
    if (!gather) {
        for (int i = tid; i < 64 * FF; i += 256) zsh[i] = zt[(size_t)m0b * FF + i];
    } else {
        // in-tile 16-dim aggregation from xsD (4 threads/row) — verified in R7
        int r = tid >> 2, p = tid & 3, half = p & 1, eo = p >> 1;
        int n = m0b + r;
        float a[8];
#pragma unroll
        for (int k = 0; k < 8; k++) a[k] = 0.f;
        if (n < NN) {
            int j0 = rp[n], j1 = rp[n + 1];
            for (int j = j0 + eo; j < j1; j += 2) {
                int s = csr[j];
                uint4 v = *(const uint4*)(xsD + (size_t)s * FF + half * 8);
                addrow(a, v);
            }
        }
#pragma unroll
        for (int k = 0; k < 8; k++) a[k] += __shfl_xor(a[k], 2);
        if (n < NN && eo == 0) {
            uint4 sv = *(const uint4*)(xsD + (size_t)n * FF + half * 8);
            addrow(a, sv);
            float dn = dinvN[n];
#pragma unroll
            for (int k = 0; k < 8; k++) zsh[r * FF + half * 8 + k] = a[k] * dn;
        }
    }
    __syncthreads();
    short8 hgf[4];
    hg_frag(zsh, Wg, gbs, wid, mr, q, hgf);
    f32x4 acc[8];
#pragma unroll
    for (int i = 0; i < 8; i++) acc[i] = (f32x4){0.f, 0.f, 0.f, 0.f};
#pragma unroll
    for (int ki = 0; ki < 8; ki++) {
        const unsigned short* Ab = (ki < 4) ? a0 : a1;
        int kin = (ki & 3) * 32 + q * 8;
        short8 af = *(const short8*)(Ab + (size_t)(m0 + mr) * HH + kin);
#pragma unroll
        for (int nt = 0; nt < 8; nt++) {
            short8 bf = *(const short8*)(Bpk + (size_t)((ki * 8 + nt) * 64 + lane) * 8);
            acc[nt] = __builtin_amdgcn_mfma_f32_16x16x32_bf16(af, bf, acc[nt], 0, 0, 0);
        }
    }
#pragma unroll
    for (int k2 = 0; k2 < 4; k2++) {
#pragma unroll
        for (int nt = 0; nt < 8; nt++) {
            short8 bf = *(const short8*)(Bpk + (size_t)(((8 + k2) * 8 + nt) * 64 + lane) * 8);
            acc[nt] = __builtin_amdgcn_mfma_f32_16x16x32_bf16(hgf[k2], bf, acc[nt], 0, 0, 0);
        }
    }
#pragma unroll
    for (int nt = 0; nt < 8; nt++) {
        int feat = nt * 16 + mr;
        float bv = biasS[feat];
#pragma unroll
        for (int r = 0; r < 4; r++) {
            int lrow = wid * 16 + q * 4 + r;
            unsigned short hv = f2b(acc[nt][r] + bv);
            out[(size_t)(m0b + lrow) * HH + feat] = hv;
            hsh[lrow * 136 + feat] = hv;
        }
    }
    __syncthreads();
    // head: y[n][c] = hb[c] + sum_k h[n][k]*Wh[c][k]
    {
        int r = tid >> 2, c0 = (tid & 3) * 4;
        float y0 = hbS[c0], y1 = hbS[c0 + 1], y2 = hbS[c0 + 2], y3 = hbS[c0 + 3];
        for (int k = 0; k < HH; k++) {
            float hv = blo((unsigned int)hsh[r * 136 + k]);
            y0 += hv * Wh[(c0 + 0) * HH + k];
            y1 += hv * Wh[(c0 + 1) * HH + k];
            y2 += hv * Wh[(c0 + 2) * HH + k];
            y3 += hv * Wh[(c0 + 3) * HH + k];
        }
        ysh[r * 17 + c0] = y0; ysh[r * 17 + c0 + 1] = y1;
        ysh[r * 17 + c0 + 2] = y2; ysh[r * 17 + c0 + 3] = y3;
        int gn = m0b + r;
        if (gn < NN)
            *(float4*)(yout + (size_t)gn * CC + c0) = make_float4(y0, y1, y2, y3);
    }
    __syncthreads();
    // next-step xs: xsD[n][k] = bf16(y[n][k] * dinv[n])
    if (tid < 64) {
        int gn = m0b + tid;
        if (gn < NN) {
            float dn = dinvN[gn];
            unsigned int res[8];
#pragma unroll
            for (int k = 0; k < 8; k++)
                res[k] = pck(ysh[tid * 17 + 2 * k] * dn, ysh[tid * 17 + 2 * k + 1] * dn);
            uint4* dst = (uint4*)(xsD + (size_t)gn * FF);
            dst[0] = *(uint4*)(res);
            dst[1] = *(uint4*)(res + 4);
        }
    }
}

extern "C" void kernel_launch(void* const* d_in, const int* in_sizes, int n_in,
                              void* d_out, int out_size, void* d_ws, size_t ws_size,
                              hipStream_t stream) {
    const float* x_seq  = (const float*)d_in[0];
    const int*   ei     = (const int*)d_in[1];
    const float* gcn_w  = (const float*)d_in[5];
    const float* gcn_b  = (const float*)d_in[6];
    const float* conv_w = (const float*)d_in[7];
    const float* conv_b = (const float*)d_in[8];
    const float* proj_w = (const float*)d_in[9];
    const float* proj_b = (const float*)d_in[10];
    const float* head_w = (const float*)d_in[11];
    const float* head_b = (const float*)d_in[12];
    float* outp = (float*)d_out;

    char* ws = (char*)d_ws;
    size_t off = 0;
    auto alloc = [&](size_t bytes) { void* p = ws + off; off += (bytes + 255) & ~(size_t)255; return p; };
    // persistent
    float*          dinv   = (float*)alloc((size_t)TT * NN * 4);
    int*            rowptr = (int*)alloc((size_t)TT * (NN + 1) * 4);
    unsigned short* csr    = (unsigned short*)alloc((size_t)TT * EE * 2);
    unsigned short* hb0    = (unsigned short*)alloc((size_t)NP * HH * 2);
    unsigned short* hb1    = (unsigned short*)alloc((size_t)NP * HH * 2);
    unsigned short* hb2    = (unsigned short*)alloc((size_t)NP * HH * 2);
    unsigned short* hb3    = (unsigned short*)alloc((size_t)NP * HH * 2);
    unsigned short* xsD    = (unsigned short*)alloc((size_t)NP * FF * 2);
    unsigned short* Bpk    = (unsigned short*)alloc((size_t)384 * HH * 2);
    float*          Bf32   = (float*)alloc((size_t)384 * HH * 4);
    float*          biasT  = (float*)alloc(HH * 4);
    unsigned short* Bpk2   = (unsigned short*)alloc((size_t)16 * 16 * 64 * 8 * 2);
    float*          biasP  = (float*)alloc(256 * 4);
    // transient B: encoder xs + z (all 12 steps)
    size_t tb = off;
    unsigned short* xs12 = (unsigned short*)alloc((size_t)TT * NN * FF * 2);
    float*          z12  = (float*)alloc((size_t)TT * NP * FF * 4);
    size_t compute_end = off;
    // transient A: CSR-build scratch, aliased over transient B
    off = tb;
    int* gData = (int*)alloc((size_t)TT * WPT * NB * CAP * 4);
    int* pcnt  = (int*)alloc((size_t)TT * WPT * NB * 4);
    int* bbase = (int*)alloc((size_t)TT * NB * 4);
    size_t csr_end = off;
    bool fastcsr = (csr_end <= ws_size && compute_end <= ws_size);

    // zero hb2,hb3 (read as h_{-2},h_{-1} by the first pair step; contiguous)
    k_zero<<<(NP * HH + 255) / 256, 256, 0, stream>>>((int*)hb2, NP * HH);

    if (fastcsr) {
        k_binA<<<TT * WPT, 512, 0, stream>>>(ei, gData, pcnt);
        k_bscan2<<<TT, 512, 0, stream>>>(pcnt, bbase, rowptr);
        k_placeB<<<TT * NB, 256, 0, stream>>>(gData, pcnt, bbase, rowptr, dinv, csr);
    } else {
        off = tb;
        int* cnt  = (int*)alloc((size_t)TT * NN * 4);
        int* wofs = (int*)alloc((size_t)TT * NN * 4);
        k_zero<<<(TT * NN + 255) / 256, 256, 0, stream>>>(cnt, TT * NN);
        k_count<<<(TT * EE + 255) / 256, 256, 0, stream>>>(ei, cnt);
        k_dinvF<<<(TT * NN + 255) / 256, 256, 0, stream>>>(cnt, dinv);
        k_scan<<<TT, 1024, 0, stream>>>(cnt, rowptr, wofs);
        k_place<<<(TT * EE + 255) / 256, 256, 0, stream>>>(ei, wofs, csr);
    }

    k_wprepB<<<193, 256, 0, stream>>>(conv_w, proj_w, conv_b, proj_b, Bpk, Bf32, biasT);
    k_packP<<<(16 * 16 * 64 * 8 + 256 + 255) / 256, 256, 0, stream>>>(Bf32, biasT, Bpk2, biasP);

    // encoder front-end: xs for all 12 steps, then all 12 aggregations in one launch
    k_xs<<<(TT * NN + 255) / 256, 256, 0, stream>>>(x_seq, dinv, xs12);
    k_aggX<<<TT * NBLK, 256, 0, stream>>>(xs12, csr, rowptr, dinv, z12);

    // encoder: 6 pairwise gemms. pair t: writes h_t -> hb[t%4], h_{t+1} -> hb[(t+1)%4];
    // reads h_{t-2}=hb[(t+2)%4], h_{t-1}=hb[(t+3)%4]
    unsigned short* hbuf[4] = {hb0, hb1, hb2, hb3};
    for (int t = 0; t < TT; t += 2) {
        k_gemm2<<<NP / 64, 256, 0, stream>>>(hbuf[(t + 2) & 3], hbuf[(t + 3) & 3],
                                             z12 + (size_t)t * NP * FF,
                                             z12 + (size_t)(t + 1) * NP * FF,
                                             gcn_w, gcn_b, Bpk2, biasP,
                                             hbuf[t & 3], hbuf[(t + 1) & 3]);
    }
    // decoder: t=12 reuses z(t=11); later steps gather in-tile from xsD
    const float* dinv11 = dinv + (size_t)(TT - 1) * NN;
    const int* rp11 = rowptr + (size_t)(TT - 1) * (NN + 1);
    const unsigned short* csr11 = csr + (size_t)(TT - 1) * EE;
    for (int t = TT; t < TT + HOR; t++) {
        const float* zt = (t == TT) ? (z12 + (size_t)(TT - 1) * NP * FF) : nullptr;
        k_gemmF2<<<NP / 64, 256, 0, stream>>>(hbuf[(t + 2) & 3], hbuf[(t + 3) & 3],
                                              zt, (t == TT) ? 0 : 1,
                                              gcn_w, gcn_b, Bpk, biasT, hbuf[t & 3],
                                              head_w, head_b, dinv11, rp11, csr11,
                                              xsD, outp + (size_t)(t - TT) * NN * CC);
    }
}